// Round 2
// baseline (1270.158 us; speedup 1.0000x reference)
//
#include <hip/hip_runtime.h>
#include <hip/hip_bf16.h>
#include <math.h>

typedef __bf16 bf16_t;
typedef bf16_t bf16x8 __attribute__((ext_vector_type(8)));
typedef bf16_t bf16x4 __attribute__((ext_vector_type(4)));
typedef float  f32x4  __attribute__((ext_vector_type(4)));

#define NTOK 49
#define CDIM 96
#define NH   3
#define NWIN 1024

__device__ __forceinline__ f32x4 mfma16(bf16x8 a, bf16x8 b, f32x4 c) {
    return __builtin_amdgcn_mfma_f32_16x16x32_bf16(a, b, c, 0, 0, 0);
}

// Rebuilds transposed bf16 weights + padded rpb tile every launch (ws is re-poisoned).
__global__ void prep_kernel(const float* __restrict__ qkv_w,
                            const float* __restrict__ proj_w,
                            const float* __restrict__ bias_table,
                            const int*   __restrict__ rel_idx,
                            bf16_t* __restrict__ wqT,   // [288][96]  wqT[n][k] = qkv_w[k][n]
                            bf16_t* __restrict__ wpT,   // [96][96]   wpT[n][k] = proj_w[k][n]
                            float*  __restrict__ rpbf)  // [3][64][64], -1e9 in pad cols
{
    const int stride = gridDim.x * blockDim.x;
    const int i0 = blockIdx.x * blockDim.x + threadIdx.x;
    for (int e = i0; e < 288 * 96; e += stride) {
        int n = e / 96, k = e - n * 96;
        wqT[e] = (bf16_t)qkv_w[k * 288 + n];
    }
    for (int e = i0; e < 96 * 96; e += stride) {
        int n = e / 96, k = e - n * 96;
        wpT[e] = (bf16_t)proj_w[k * 96 + n];
    }
    for (int e = i0; e < 3 * 64 * 64; e += stride) {
        int h = e >> 12, r = (e >> 6) & 63, c = e & 63;
        float v;
        if (c >= NTOK)      v = -1e9f;   // masks pad columns through both softmaxes
        else if (r >= NTOK) v = 0.0f;    // pad rows: value irrelevant, keep finite
        else                v = bias_table[rel_idx[r * NTOK + c] * NH + h];
        rpbf[e] = v;
    }
}

__global__ void __launch_bounds__(192)
wattn_kernel(const float* __restrict__ x,
             const float* __restrict__ mask,
             const float* __restrict__ qkv_b,
             const float* __restrict__ proj_b,
             const bf16_t* __restrict__ wqT,
             const bf16_t* __restrict__ wpT,
             const float*  __restrict__ rpbf,
             float* __restrict__ out)
{
    // Row strides padded (104 / 72 elems) so b128 reads land 2-way on banks (free).
    __shared__ alignas(16) bf16_t xs[64][104];     // x (qkv A), then reused as attn-out (proj A)
    __shared__ alignas(16) bf16_t qs[64][104];     // q * scale, cols = h*32+d
    __shared__ alignas(16) bf16_t kk[64][104];     // k, cols = h*32+d
    __shared__ alignas(16) bf16_t vT[96][72];      // v transposed: vT[h*32+d][m]
    __shared__ alignas(16) bf16_t ps[3][64][72];   // attn probs per head (pad cols = 0)

    const int b    = blockIdx.x;
    const int tid  = threadIdx.x;
    const int w    = tid >> 6;      // wave 0..2
    const int lane = tid & 63;
    const int r16  = lane & 15;
    const int g    = lane >> 4;     // 0..3
    const int g8   = g << 3;
    const int g4   = g << 2;

    const float scale = 0.17677669529663687f;  // 32^-0.5

    // ---- P0: stage x -> bf16 LDS via float4 loads; zero-pad rows 49..63 ----
    {
        const float* xb = x + (size_t)b * (NTOK * CDIM);
        // 64*96 = 6144 elems = 1536 float4 = 192 threads * 8 iters.
        // 4704 valid elems = 1176 float4 (exact) -> no straddle of valid/pad.
        #pragma unroll
        for (int it = 0; it < 8; ++it) {
            int q4 = tid + it * 192;           // float4 index
            int e  = q4 * 4;
            int r  = e / 96, c = e - r * 96;   // c in {0,4,...,92}: never crosses a row
            float4 v;
            if (q4 < 1176) v = *reinterpret_cast<const float4*>(xb + e);
            else           v = make_float4(0.f, 0.f, 0.f, 0.f);
            bf16x4 o = { (bf16_t)v.x, (bf16_t)v.y, (bf16_t)v.z, (bf16_t)v.w };
            *reinterpret_cast<bf16x4*>(&xs[r][c]) = o;
        }
    }
    __syncthreads();

    // ---- P1: qkv = xs @ qkv_w + b.  Wave w owns output cols [w*96, w*96+96) ----
    {
        bf16x8 afr[4][3];
        #pragma unroll
        for (int mt = 0; mt < 4; ++mt)
            #pragma unroll
            for (int ks = 0; ks < 3; ++ks)
                afr[mt][ks] = *reinterpret_cast<const bf16x8*>(&xs[mt * 16 + r16][ks * 32 + g8]);

        #pragma unroll
        for (int nt6 = 0; nt6 < 6; ++nt6) {
            const int col = (w * 6 + nt6) * 16 + r16;   // 0..287 (D col for this lane)
            f32x4 acc[4];
            #pragma unroll
            for (int mt = 0; mt < 4; ++mt) acc[mt] = (f32x4){0.f, 0.f, 0.f, 0.f};
            #pragma unroll
            for (int ks = 0; ks < 3; ++ks) {
                bf16x8 bfr = *reinterpret_cast<const bf16x8*>(wqT + col * 96 + ks * 32 + g8);
                #pragma unroll
                for (int mt = 0; mt < 4; ++mt) acc[mt] = mfma16(afr[mt][ks], bfr, acc[mt]);
            }
            const float bias = qkv_b[col];
            #pragma unroll
            for (int mt = 0; mt < 4; ++mt)
                #pragma unroll
                for (int j = 0; j < 4; ++j) {
                    const int row = mt * 16 + g4 + j;
                    const float v = acc[mt][j] + bias;
                    if (w == 0)      qs[row][col]       = (bf16_t)(v * scale);
                    else if (w == 1) kk[row][col - 96]  = (bf16_t)v;
                    else             vT[col - 192][row] = (bf16_t)v;   // transpose v at write
                }
        }
    }
    __syncthreads();

    // ---- P2: per-head (wave=head) QK^T + rpb + mask + softmax x2 -> ps ----
    const int h = w;
    {
        bf16x8 qa[4], kb[4];
        #pragma unroll
        for (int t = 0; t < 4; ++t) {
            qa[t] = *reinterpret_cast<const bf16x8*>(&qs[t * 16 + r16][h * 32 + g8]);
            kb[t] = *reinterpret_cast<const bf16x8*>(&kk[t * 16 + r16][h * 32 + g8]);
        }
        f32x4 s[4][4];
        #pragma unroll
        for (int mt = 0; mt < 4; ++mt)
            #pragma unroll
            for (int nt = 0; nt < 4; ++nt) {
                f32x4 z = (f32x4){0.f, 0.f, 0.f, 0.f};
                s[mt][nt] = mfma16(qa[mt], kb[nt], z);
            }
        const float* rpbh = rpbf + h * 4096;
        const float* mrow = mask + (size_t)(b & (NWIN - 1)) * (NTOK * NTOK);
        #pragma unroll
        for (int mt = 0; mt < 4; ++mt)
            #pragma unroll
            for (int j = 0; j < 4; ++j) {
                const int row = mt * 16 + g4 + j;
                #pragma unroll
                for (int nt = 0; nt < 4; ++nt) {
                    const int col = nt * 16 + r16;
                    float v = s[mt][nt][j] + rpbh[(row << 6) + col];
                    if (row < NTOK && col < NTOK) v += mrow[row * NTOK + col];
                    s[mt][nt][j] = v;
                }
            }
        // Row r lives in the 16 lanes of group g across 4 nt-registers.
        #pragma unroll
        for (int mt = 0; mt < 4; ++mt)
            #pragma unroll
            for (int j = 0; j < 4; ++j) {
                float m = fmaxf(fmaxf(s[mt][0][j], s[mt][1][j]), fmaxf(s[mt][2][j], s[mt][3][j]));
                m = fmaxf(m, __shfl_xor(m, 1));
                m = fmaxf(m, __shfl_xor(m, 2));
                m = fmaxf(m, __shfl_xor(m, 4));
                m = fmaxf(m, __shfl_xor(m, 8));
                float e1[4];
                float sum = 0.f;
                #pragma unroll
                for (int nt = 0; nt < 4; ++nt) { e1[nt] = __expf(s[mt][nt][j] - m); sum += e1[nt]; }
                sum += __shfl_xor(sum, 1);
                sum += __shfl_xor(sum, 2);
                sum += __shfl_xor(sum, 4);
                sum += __shfl_xor(sum, 8);
                const float inv = 1.0f / sum;
                // second softmax: logits = probs, pad cols re-masked
                float p[4];
                float m2 = -1e30f;
                #pragma unroll
                for (int nt = 0; nt < 4; ++nt) {
                    const int col = nt * 16 + r16;
                    p[nt] = (col < NTOK) ? e1[nt] * inv : -1e9f;
                    m2 = fmaxf(m2, p[nt]);
                }
                m2 = fmaxf(m2, __shfl_xor(m2, 1));
                m2 = fmaxf(m2, __shfl_xor(m2, 2));
                m2 = fmaxf(m2, __shfl_xor(m2, 4));
                m2 = fmaxf(m2, __shfl_xor(m2, 8));
                float sum2 = 0.f;
                #pragma unroll
                for (int nt = 0; nt < 4; ++nt) { p[nt] = __expf(p[nt] - m2); sum2 += p[nt]; }
                sum2 += __shfl_xor(sum2, 1);
                sum2 += __shfl_xor(sum2, 2);
                sum2 += __shfl_xor(sum2, 4);
                sum2 += __shfl_xor(sum2, 8);
                const float inv2 = 1.0f / sum2;
                const int row = mt * 16 + g4 + j;
                #pragma unroll
                for (int nt = 0; nt < 4; ++nt)
                    ps[h][row][nt * 16 + r16] = (bf16_t)(p[nt] * inv2);  // pad cols -> exact 0
            }
    }

    // ---- P3: out_h = P @ V (per-wave data; no barrier needed before this) ----
    {
        #pragma unroll
        for (int nt = 0; nt < 2; ++nt) {
            const int dcol = h * 32 + nt * 16 + r16;   // output feature index
            bf16x8 vb0 = *reinterpret_cast<const bf16x8*>(&vT[dcol][g8]);
            bf16x8 vb1 = *reinterpret_cast<const bf16x8*>(&vT[dcol][32 + g8]);
            #pragma unroll
            for (int mt = 0; mt < 4; ++mt) {
                bf16x8 pa0 = *reinterpret_cast<const bf16x8*>(&ps[h][mt * 16 + r16][g8]);
                bf16x8 pa1 = *reinterpret_cast<const bf16x8*>(&ps[h][mt * 16 + r16][32 + g8]);
                f32x4 o = (f32x4){0.f, 0.f, 0.f, 0.f};
                o = mfma16(pa0, vb0, o);
                o = mfma16(pa1, vb1, o);
                #pragma unroll
                for (int j = 0; j < 4; ++j)
                    xs[mt * 16 + g4 + j][dcol] = (bf16_t)o[j];   // xs reused as proj input
            }
        }
    }
    __syncthreads();

    // ---- P4: final = oh @ proj_w + b.  Wave w owns cols [w*32, w*32+32) ----
    {
        #pragma unroll
        for (int n2 = 0; n2 < 2; ++n2) {
            const int col = w * 32 + n2 * 16 + r16;
            f32x4 acc[4];
            #pragma unroll
            for (int mt = 0; mt < 4; ++mt) acc[mt] = (f32x4){0.f, 0.f, 0.f, 0.f};
            #pragma unroll
            for (int ks = 0; ks < 3; ++ks) {
                bf16x8 bfr = *reinterpret_cast<const bf16x8*>(wpT + col * 96 + ks * 32 + g8);
                #pragma unroll
                for (int mt = 0; mt < 4; ++mt) {
                    bf16x8 oa = *reinterpret_cast<const bf16x8*>(&xs[mt * 16 + r16][ks * 32 + g8]);
                    acc[mt] = mfma16(oa, bfr, acc[mt]);
                }
            }
            const float pb = proj_b[col];
            #pragma unroll
            for (int mt = 0; mt < 4; ++mt)
                #pragma unroll
                for (int j = 0; j < 4; ++j) {
                    const int row = mt * 16 + g4 + j;
                    if (row < NTOK)
                        out[((size_t)b * NTOK + row) * CDIM + col] = acc[mt][j] + pb;
                }
        }
    }
}

extern "C" void kernel_launch(void* const* d_in, const int* in_sizes, int n_in,
                              void* d_out, int out_size, void* d_ws, size_t ws_size,
                              hipStream_t stream) {
    const float* x          = (const float*)d_in[0];
    const float* mask       = (const float*)d_in[1];
    const float* qkv_w      = (const float*)d_in[2];
    const float* qkv_b      = (const float*)d_in[3];
    const float* proj_w     = (const float*)d_in[4];
    const float* proj_b     = (const float*)d_in[5];
    const float* bias_table = (const float*)d_in[6];
    const int*   rel_idx    = (const int*)d_in[7];
    float* out = (float*)d_out;

    char* ws = (char*)d_ws;
    bf16_t* wqT  = (bf16_t*)(ws);                      // 55296 B
    bf16_t* wpT  = (bf16_t*)(ws + 55296);              // 18432 B
    float*  rpbf = (float*) (ws + 55296 + 18432);      // 49152 B

    prep_kernel<<<64, 256, 0, stream>>>(qkv_w, proj_w, bias_table, rel_idx, wqT, wpT, rpbf);

    const int nwin = in_sizes[0] / (NTOK * CDIM);      // 16384
    wattn_kernel<<<nwin, 192, 0, stream>>>(x, mask, qkv_b, proj_b, wqT, wpT, rpbf, out);
}

// Round 4
// 887.307 us; speedup vs baseline: 1.4315x; 1.4315x over previous
//
#include <hip/hip_runtime.h>
#include <hip/hip_bf16.h>
#include <math.h>

typedef __bf16 bf16_t;
typedef bf16_t bf16x8 __attribute__((ext_vector_type(8)));
typedef bf16_t bf16x4 __attribute__((ext_vector_type(4)));
typedef float  f32x4  __attribute__((ext_vector_type(4)));
typedef unsigned int u32;

#define NTOK 49
#define CDIM 96
#define NH   3
#define NWIN 1024

__device__ __forceinline__ f32x4 mfma16(bf16x8 a, bf16x8 b, f32x4 c) {
    return __builtin_amdgcn_mfma_f32_16x16x32_bf16(a, b, c, 0, 0, 0);
}

__device__ __forceinline__ u32 pk2(float lo, float hi) {
    union { bf16_t h[2]; u32 u; } t;
    t.h[0] = (bf16_t)lo; t.h[1] = (bf16_t)hi;
    return t.u;
}

// Rebuilds transposed bf16 weights + padded rpb tile every launch (ws is re-poisoned).
__global__ void prep_kernel(const float* __restrict__ qkv_w,
                            const float* __restrict__ proj_w,
                            const float* __restrict__ bias_table,
                            const int*   __restrict__ rel_idx,
                            bf16_t* __restrict__ wqT,   // [288][96]  wqT[n][k] = qkv_w[k][n]
                            bf16_t* __restrict__ wpT,   // [96][96]   wpT[n][k] = proj_w[k][n]
                            float*  __restrict__ rpbf)  // [3][64][64], -1e9 in pad key cols
{
    const int stride = gridDim.x * blockDim.x;
    const int i0 = blockIdx.x * blockDim.x + threadIdx.x;
    for (int e = i0; e < 288 * 96; e += stride) {
        int n = e / 96, k = e - n * 96;
        wqT[e] = (bf16_t)qkv_w[k * 288 + n];
    }
    for (int e = i0; e < 96 * 96; e += stride) {
        int n = e / 96, k = e - n * 96;
        wpT[e] = (bf16_t)proj_w[k * 96 + n];
    }
    for (int e = i0; e < 3 * 64 * 64; e += stride) {
        int h = e >> 12, r = (e >> 6) & 63, c = e & 63;
        float v;
        if (c >= NTOK)      v = -1e9f;   // pad keys -> exp underflows to exact 0
        else if (r >= NTOK) v = 0.0f;    // pad query rows: finite garbage, never stored
        else                v = bias_table[rel_idx[r * NTOK + c] * NH + h];
        rpbf[e] = v;
    }
}

// LDS plan (40,448 B -> 4 blocks/CU):
//   [0, 13824)       xs[64][104] (P0/P1 A-tile)  -- aliased by vT[96][72] after afr loads
//   [13824, 27136)   qs[64][104] (q*scale)       -- aliased by attn-out (per-wave disjoint cols)
//   [27136, 40448)   kk[64][104] (k)
__global__ void __launch_bounds__(192, 3)
wattn_kernel(const float* __restrict__ x,
             const float* __restrict__ mask,
             const float* __restrict__ qkv_b,
             const float* __restrict__ proj_b,
             const bf16_t* __restrict__ wqT,
             const bf16_t* __restrict__ wpT,
             const float*  __restrict__ rpbf,
             float* __restrict__ out)
{
    __shared__ alignas(16) char smem[40448];
    bf16_t (*xs)[104] = reinterpret_cast<bf16_t(*)[104]>(smem);
    bf16_t (*vT)[72]  = reinterpret_cast<bf16_t(*)[72]>(smem);
    bf16_t (*qs)[104] = reinterpret_cast<bf16_t(*)[104]>(smem + 13824);
    bf16_t (*kk)[104] = reinterpret_cast<bf16_t(*)[104]>(smem + 27136);

    const int b    = blockIdx.x;
    const int tid  = threadIdx.x;
    const int w    = tid >> 6;      // wave 0..2
    const int lane = tid & 63;
    const int r16  = lane & 15;
    const int g    = lane >> 4;     // 0..3
    const int g8   = g << 3;
    const int g4   = g << 2;

    const float scale = 0.17677669529663687f;  // 32^-0.5

    // ---- P0: stage x -> bf16 LDS via float4 loads; zero-pad rows 49..63 ----
    {
        const float* xb = x + (size_t)b * (NTOK * CDIM);
        #pragma unroll
        for (int it = 0; it < 8; ++it) {
            int q4 = tid + it * 192;           // float4 index; 1176 valid, 1536 total
            int e  = q4 * 4;
            int r  = e / 96, c = e - r * 96;   // c in {0,4,...,92}: never crosses a row
            float4 v;
            if (q4 < 1176) v = *reinterpret_cast<const float4*>(xb + e);
            else           v = make_float4(0.f, 0.f, 0.f, 0.f);
            bf16x4 o = { (bf16_t)v.x, (bf16_t)v.y, (bf16_t)v.z, (bf16_t)v.w };
            *reinterpret_cast<bf16x4*>(&xs[r][c]) = o;
        }
    }
    __syncthreads();

    // ---- P1: qkv = xs @ qkv_w + b.  Wave w owns output cols [w*96, w*96+96) ----
    {
        bf16x8 afr[4][3];
        #pragma unroll
        for (int mt = 0; mt < 4; ++mt)
            #pragma unroll
            for (int ks = 0; ks < 3; ++ks)
                afr[mt][ks] = *reinterpret_cast<const bf16x8*>(&xs[mt * 16 + r16][ks * 32 + g8]);

        __syncthreads();   // xs fully consumed into regs; vT may now overwrite it

        #pragma unroll
        for (int nt6 = 0; nt6 < 6; ++nt6) {
            const int col = (w * 6 + nt6) * 16 + r16;   // 0..287
            f32x4 acc[4];
            #pragma unroll
            for (int mt = 0; mt < 4; ++mt) acc[mt] = (f32x4){0.f, 0.f, 0.f, 0.f};
            #pragma unroll
            for (int ks = 0; ks < 3; ++ks) {
                bf16x8 bfr = *reinterpret_cast<const bf16x8*>(wqT + col * 96 + ks * 32 + g8);
                #pragma unroll
                for (int mt = 0; mt < 4; ++mt) acc[mt] = mfma16(afr[mt][ks], bfr, acc[mt]);
            }
            const float bias = qkv_b[col];
            #pragma unroll
            for (int mt = 0; mt < 4; ++mt)
                #pragma unroll
                for (int j = 0; j < 4; ++j) {
                    const int row = mt * 16 + g4 + j;
                    const float v = acc[mt][j] + bias;
                    if (w == 0)      qs[row][col]       = (bf16_t)(v * scale);
                    else if (w == 1) kk[row][col - 96]  = (bf16_t)v;
                    else             vT[col - 192][row] = (bf16_t)v;   // transpose v at write
                }
        }
    }
    __syncthreads();

    // ---- P2+P3: per-head (wave=head), swapped QK^T -> in-register double softmax -> PV ----
    const int h = w;
    {
        bf16x8 qa[4], kb[4], vb[2][2];
        #pragma unroll
        for (int t = 0; t < 4; ++t) {
            qa[t] = *reinterpret_cast<const bf16x8*>(&qs[t * 16 + r16][h * 32 + g8]);
            kb[t] = *reinterpret_cast<const bf16x8*>(&kk[t * 16 + r16][h * 32 + g8]);
        }
        #pragma unroll
        for (int dt = 0; dt < 2; ++dt)
            #pragma unroll
            for (int c = 0; c < 2; ++c)
                vb[dt][c] = *reinterpret_cast<const bf16x8*>(&vT[h * 32 + dt * 16 + r16][c * 32 + g8]);

        const float* rpbh = rpbf + h * 4096;
        const float* mrow = mask + (size_t)(b & (NWIN - 1)) * (NTOK * NTOK);
        const int srcA = ((g & 1) << 5) + r16;   // lane holding low half of our key chunk
        const int srcB = srcA + 16;
        const bool lo = (g < 2);

        #pragma unroll
        for (int nt = 0; nt < 4; ++nt) {
            // S^T tiles: sv[mt][j] = S[q = nt*16+r16][key = mt*16+g4+j]
            f32x4 sv[4];
            #pragma unroll
            for (int mt = 0; mt < 4; ++mt) {
                f32x4 z = (f32x4){0.f, 0.f, 0.f, 0.f};
                sv[mt] = mfma16(kb[mt], qa[nt], z);
            }
            const int q = nt * 16 + r16;
            const int rpbase = q << 6;
            const int mbase  = q * NTOK;
            float s[4][4];
            #pragma unroll
            for (int mt = 0; mt < 4; ++mt)
                #pragma unroll
                for (int j = 0; j < 4; ++j) {
                    const int key = mt * 16 + g4 + j;
                    float v = sv[mt][j] + rpbh[rpbase + key];
                    // key < 49 always for mt<3; for mt=3 only (g==0,j==0)
                    if ((mt < 3 || (j == 0 && g == 0)) && q < NTOK)
                        v += mrow[mbase + key];
                    s[mt][j] = v;
                }

            // softmax 1: row q spans this lane's 16 values x 4 g-lanes
            float mx = -3.0e38f;
            #pragma unroll
            for (int mt = 0; mt < 4; ++mt)
                #pragma unroll
                for (int j = 0; j < 4; ++j) mx = fmaxf(mx, s[mt][j]);
            mx = fmaxf(mx, __shfl_xor(mx, 16));
            mx = fmaxf(mx, __shfl_xor(mx, 32));
            float e1[4][4];
            float sum1 = 0.f;
            #pragma unroll
            for (int mt = 0; mt < 4; ++mt)
                #pragma unroll
                for (int j = 0; j < 4; ++j) {
                    float t = __expf(s[mt][j] - mx);   // pad keys: exp(-1e9) == exact 0
                    e1[mt][j] = t; sum1 += t;
                }
            sum1 += __shfl_xor(sum1, 16);
            sum1 += __shfl_xor(sum1, 32);
            const float inv1 = __builtin_amdgcn_rcpf(sum1);

            // softmax 2 on p in [0,1]: no max needed; pads give exp(0)=1 -> subtract 15
            float e2[4][4];
            float sum2 = 0.f;
            #pragma unroll
            for (int mt = 0; mt < 4; ++mt)
                #pragma unroll
                for (int j = 0; j < 4; ++j) {
                    float t = __expf(e1[mt][j] * inv1);
                    e2[mt][j] = t; sum2 += t;
                }
            sum2 += __shfl_xor(sum2, 16);
            sum2 += __shfl_xor(sum2, 32);
            sum2 -= 15.0f;                              // remove the 15 pad-key exp(0) terms
            const float inv2 = __builtin_amdgcn_rcpf(sum2);

            // pack P row-chunks to bf16 dwords; zero pad keys (mt=3, key>48)
            u32 d01[4], d23[4];
            #pragma unroll
            for (int mt = 0; mt < 4; ++mt) {
                float p0 = e2[mt][0] * inv2, p1 = e2[mt][1] * inv2;
                float p2 = e2[mt][2] * inv2, p3 = e2[mt][3] * inv2;
                if (mt == 3) { p0 = (g == 0) ? p0 : 0.f; p1 = 0.f; p2 = 0.f; p3 = 0.f; }
                d01[mt] = pk2(p0, p1);
                d23[mt] = pk2(p2, p3);
            }
            // lane transpose: dst (g,r16) chunk c gathers keys 32c+8g..+7 from
            // src lanes (g&1)*32+r16 (+16), rounds mt = 2c + (g>>1)
            u32 m0a0 = __shfl(d01[0], srcA), m0a1 = __shfl(d23[0], srcA);
            u32 m0b0 = __shfl(d01[0], srcB), m0b1 = __shfl(d23[0], srcB);
            u32 m1a0 = __shfl(d01[1], srcA), m1a1 = __shfl(d23[1], srcA);
            u32 m1b0 = __shfl(d01[1], srcB), m1b1 = __shfl(d23[1], srcB);
            u32 m2a0 = __shfl(d01[2], srcA), m2a1 = __shfl(d23[2], srcA);
            u32 m2b0 = __shfl(d01[2], srcB), m2b1 = __shfl(d23[2], srcB);
            u32 m3a0 = __shfl(d01[3], srcA), m3a1 = __shfl(d23[3], srcA);
            u32 m3b0 = __shfl(d01[3], srcB), m3b1 = __shfl(d23[3], srcB);

            union U8 { u32 d[4]; bf16x8 v; } ua, ub;
            ua.d[0] = lo ? m0a0 : m1a0;  ua.d[1] = lo ? m0a1 : m1a1;
            ua.d[2] = lo ? m0b0 : m1b0;  ua.d[3] = lo ? m0b1 : m1b1;
            ub.d[0] = lo ? m2a0 : m3a0;  ub.d[1] = lo ? m2a1 : m3a1;
            ub.d[2] = lo ? m2b0 : m3b0;  ub.d[3] = lo ? m2b1 : m3b1;

            // PV: out[q=nt*16+g4+j][d=dt*16+r16 (+h*32)]
            #pragma unroll
            for (int dt = 0; dt < 2; ++dt) {
                f32x4 z = (f32x4){0.f, 0.f, 0.f, 0.f};
                f32x4 o = mfma16(ua.v, vb[dt][0], z);
                o = mfma16(ub.v, vb[dt][1], o);
                const int dcol = h * 32 + dt * 16 + r16;
                #pragma unroll
                for (int j = 0; j < 4; ++j)
                    qs[nt * 16 + g4 + j][dcol] = (bf16_t)o[j];   // attn-out into qs-space
            }
        }
    }
    __syncthreads();

    // ---- P4: final = attn_out @ proj_w + b.  Wave w owns cols [w*32, w*32+32) ----
    {
        #pragma unroll
        for (int n2 = 0; n2 < 2; ++n2) {
            const int col = w * 32 + n2 * 16 + r16;
            f32x4 acc[4];
            #pragma unroll
            for (int mt = 0; mt < 4; ++mt) acc[mt] = (f32x4){0.f, 0.f, 0.f, 0.f};
            #pragma unroll
            for (int ks = 0; ks < 3; ++ks) {
                bf16x8 bfr = *reinterpret_cast<const bf16x8*>(wpT + col * 96 + ks * 32 + g8);
                #pragma unroll
                for (int mt = 0; mt < 4; ++mt) {
                    bf16x8 oa = *reinterpret_cast<const bf16x8*>(&qs[mt * 16 + r16][ks * 32 + g8]);
                    acc[mt] = mfma16(oa, bfr, acc[mt]);
                }
            }
            const float pb = proj_b[col];
            #pragma unroll
            for (int mt = 0; mt < 4; ++mt)
                #pragma unroll
                for (int j = 0; j < 4; ++j) {
                    const int row = mt * 16 + g4 + j;
                    if (row < NTOK)
                        out[((size_t)b * NTOK + row) * CDIM + col] = acc[mt][j] + pb;
                }
        }
    }
}

extern "C" void kernel_launch(void* const* d_in, const int* in_sizes, int n_in,
                              void* d_out, int out_size, void* d_ws, size_t ws_size,
                              hipStream_t stream) {
    const float* x          = (const float*)d_in[0];
    const float* mask       = (const float*)d_in[1];
    const float* qkv_w      = (const float*)d_in[2];
    const float* qkv_b      = (const float*)d_in[3];
    const float* proj_w     = (const float*)d_in[4];
    const float* proj_b     = (const float*)d_in[5];
    const float* bias_table = (const float*)d_in[6];
    const int*   rel_idx    = (const int*)d_in[7];
    float* out = (float*)d_out;

    char* ws = (char*)d_ws;
    bf16_t* wqT  = (bf16_t*)(ws);                      // 55296 B
    bf16_t* wpT  = (bf16_t*)(ws + 55296);              // 18432 B
    float*  rpbf = (float*) (ws + 55296 + 18432);      // 49152 B

    prep_kernel<<<64, 256, 0, stream>>>(qkv_w, proj_w, bias_table, rel_idx, wqT, wpT, rpbf);

    const int nwin = in_sizes[0] / (NTOK * CDIM);      // 16384
    wattn_kernel<<<nwin, 192, 0, stream>>>(x, mask, qkv_b, proj_b, wqT, wpT, rpbf, out);
}

// Round 5
// 765.621 us; speedup vs baseline: 1.6590x; 1.1589x over previous
//
#include <hip/hip_runtime.h>
#include <hip/hip_bf16.h>
#include <math.h>

typedef __bf16 bf16_t;
typedef bf16_t bf16x8 __attribute__((ext_vector_type(8)));
typedef bf16_t bf16x4 __attribute__((ext_vector_type(4)));
typedef float  f32x4  __attribute__((ext_vector_type(4)));
typedef unsigned int u32;

#define NTOK 49
#define CDIM 96
#define NH   3
#define NWIN 1024

__device__ __forceinline__ f32x4 mfma16(bf16x8 a, bf16x8 b, f32x4 c) {
    return __builtin_amdgcn_mfma_f32_16x16x32_bf16(a, b, c, 0, 0, 0);
}

__device__ __forceinline__ u32 pk2(float lo, float hi) {
    union { bf16_t h[2]; u32 u; } t;
    t.h[0] = (bf16_t)lo; t.h[1] = (bf16_t)hi;
    return t.u;
}

// Rebuilds bf16 weights + padded rpb (+ optional padded mask) every launch.
__global__ void prep_kernel(const float* __restrict__ qkv_w,
                            const float* __restrict__ proj_w,
                            const float* __restrict__ bias_table,
                            const int*   __restrict__ rel_idx,
                            const float* __restrict__ mask,
                            bf16_t* __restrict__ wqT,   // [288][96]  wqT[n][k] = qkv_w[k][n]
                            bf16_t* __restrict__ wpT,   // [96][96]   wpT[n][k] = proj_w[k][n]
                            float*  __restrict__ rpbf,  // [3][64][64], -1e9 in pad key cols
                            float*  __restrict__ maskp) // [1024][64][64] padded mask (optional)
{
    const int stride = gridDim.x * blockDim.x;
    const int i0 = blockIdx.x * blockDim.x + threadIdx.x;
    for (int e = i0; e < 288 * 96; e += stride) {
        int n = e / 96, k = e - n * 96;
        wqT[e] = (bf16_t)qkv_w[k * 288 + n];
    }
    for (int e = i0; e < 96 * 96; e += stride) {
        int n = e / 96, k = e - n * 96;
        wpT[e] = (bf16_t)proj_w[k * 96 + n];
    }
    for (int e = i0; e < 3 * 64 * 64; e += stride) {
        int h = e >> 12, r = (e >> 6) & 63, c = e & 63;
        float v;
        if (c >= NTOK)      v = -1e9f;   // pad keys -> exp underflows to exact 0
        else if (r >= NTOK) v = 0.0f;
        else                v = bias_table[rel_idx[r * NTOK + c] * NH + h];
        rpbf[e] = v;
    }
    if (maskp) {
        for (int e = i0; e < NWIN * 64 * 64; e += stride) {
            int widx = e >> 12, r = (e >> 6) & 63, c = e & 63;
            maskp[e] = (r < NTOK && c < NTOK) ? mask[widx * (NTOK * NTOK) + r * NTOK + c] : 0.0f;
        }
    }
}

// One window per block, wave = head. LDS = xs only (13,312 B).
// q,k computed TRANSPOSED (A=wqT rows, B=x frags) and v non-transposed, so all
// three convert to MFMA operand layouts via uniform-j lane shuffles (no LDS).
template <bool MP>
__global__ void __launch_bounds__(192, 4)
wattn_kernel(const float* __restrict__ x,
             const float* __restrict__ mask,
             const float* __restrict__ maskp,
             const float* __restrict__ qkv_b,
             const float* __restrict__ proj_b,
             const bf16_t* __restrict__ wqT,
             const bf16_t* __restrict__ wpT,
             const float*  __restrict__ rpbf,
             float* __restrict__ out)
{
    __shared__ alignas(16) bf16_t xs[64][104];   // x tile; later reused as attn-out

    const int b    = blockIdx.x;
    const int tid  = threadIdx.x;
    const int h    = tid >> 6;      // wave = head
    const int lane = tid & 63;
    const int r16  = lane & 15;
    const int g    = lane >> 4;
    const int g8   = g << 3;
    const int g4   = g << 2;
    const float scale = 0.17677669529663687f;    // 32^-0.5

    const int srcA = ((g & 1) << 5) + r16;
    const int srcB = srcA + 16;
    const bool hi  = (g >= 2);
    const bool lo  = !hi;

    // ---- P0: stage x -> bf16 LDS via float4 loads; zero-pad rows 49..63 ----
    {
        const float* xb = x + (size_t)b * (NTOK * CDIM);
        #pragma unroll
        for (int it = 0; it < 8; ++it) {
            int q4 = tid + it * 192;
            int e  = q4 * 4;
            int r  = e / 96, c = e - r * 96;
            float4 v;
            if (q4 < 1176) v = *reinterpret_cast<const float4*>(xb + e);
            else           v = make_float4(0.f, 0.f, 0.f, 0.f);
            bf16x4 o = { (bf16_t)v.x, (bf16_t)v.y, (bf16_t)v.z, (bf16_t)v.w };
            *reinterpret_cast<bf16x4*>(&xs[r][c]) = o;
        }
    }
    __syncthreads();

    // ---- P1: per-wave-head qkv, all outputs -> registers ----
    bf16x8 qa[4], kb[4], vb[2][2];
    {
        // q^T and k^T: D[d][tok] tiles, then shuffle into B/A fragments
        u32 d01[2][4], d23[2][4];
        #pragma unroll
        for (int sec = 0; sec < 2; ++sec) {          // 0 = q, 1 = k
            const int base = sec * 96 + h * 32;
            #pragma unroll
            for (int dt = 0; dt < 2; ++dt) {
                bf16x8 wf[3];
                #pragma unroll
                for (int ks = 0; ks < 3; ++ks)
                    wf[ks] = *reinterpret_cast<const bf16x8*>(wqT + (base + dt * 16 + r16) * 96 + ks * 32 + g8);
                float4 b4 = *reinterpret_cast<const float4*>(qkv_b + base + dt * 16 + g4);
                #pragma unroll
                for (int t = 0; t < 4; ++t) {
                    f32x4 acc = (f32x4){0.f, 0.f, 0.f, 0.f};
                    #pragma unroll
                    for (int ks = 0; ks < 3; ++ks)
                        acc = mfma16(wf[ks], *reinterpret_cast<const bf16x8*>(&xs[t * 16 + r16][ks * 32 + g8]), acc);
                    // acc[j] = (x@W)[tok=t*16+r16][d=dt*16+g4+j] + bias
                    if (sec == 0) {
                        d01[dt][t] = pk2((acc[0] + b4.x) * scale, (acc[1] + b4.y) * scale);
                        d23[dt][t] = pk2((acc[2] + b4.z) * scale, (acc[3] + b4.w) * scale);
                    } else {
                        d01[dt][t] = pk2(acc[0] + b4.x, acc[1] + b4.y);
                        d23[dt][t] = pk2(acc[2] + b4.z, acc[3] + b4.w);
                    }
                }
            }
            // fragment build: lane (g,r16) dword w holds d-pair (g8+2w, g8+2w+1) of tok=t*16+r16
            #pragma unroll
            for (int t = 0; t < 4; ++t) {
                u32 a0, b0;
                union U8 { u32 d[4]; bf16x8 v; } u;
                a0 = __shfl(d01[0][t], srcA); b0 = __shfl(d01[1][t], srcA); u.d[0] = hi ? b0 : a0;
                a0 = __shfl(d23[0][t], srcA); b0 = __shfl(d23[1][t], srcA); u.d[1] = hi ? b0 : a0;
                a0 = __shfl(d01[0][t], srcB); b0 = __shfl(d01[1][t], srcB); u.d[2] = hi ? b0 : a0;
                a0 = __shfl(d23[0][t], srcB); b0 = __shfl(d23[1][t], srcB); u.d[3] = hi ? b0 : a0;
                if (sec == 0) qa[t] = u.v; else kb[t] = u.v;
            }
        }
        // v (non-transposed): D[tok][d] tiles -> B fragments (P-transpose pattern)
        u32 vd01[4][2], vd23[4][2];
        {
            bf16x8 vwf[2][3];
            float vbias[2];
            #pragma unroll
            for (int dt = 0; dt < 2; ++dt) {
                #pragma unroll
                for (int ks = 0; ks < 3; ++ks)
                    vwf[dt][ks] = *reinterpret_cast<const bf16x8*>(wqT + (192 + h * 32 + dt * 16 + r16) * 96 + ks * 32 + g8);
                vbias[dt] = qkv_b[192 + h * 32 + dt * 16 + r16];
            }
            #pragma unroll
            for (int mt = 0; mt < 4; ++mt) {
                bf16x8 af[3];
                #pragma unroll
                for (int ks = 0; ks < 3; ++ks)
                    af[ks] = *reinterpret_cast<const bf16x8*>(&xs[mt * 16 + r16][ks * 32 + g8]);
                #pragma unroll
                for (int dt = 0; dt < 2; ++dt) {
                    f32x4 acc = (f32x4){0.f, 0.f, 0.f, 0.f};
                    #pragma unroll
                    for (int ks = 0; ks < 3; ++ks)
                        acc = mfma16(af[ks], vwf[dt][ks], acc);
                    vd01[mt][dt] = pk2(acc[0] + vbias[dt], acc[1] + vbias[dt]);
                    vd23[mt][dt] = pk2(acc[2] + vbias[dt], acc[3] + vbias[dt]);
                }
            }
            #pragma unroll
            for (int dt = 0; dt < 2; ++dt)
                #pragma unroll
                for (int c = 0; c < 2; ++c) {
                    u32 a0, b0;
                    union U8 { u32 d[4]; bf16x8 v; } u;
                    a0 = __shfl(vd01[2 * c][dt], srcA); b0 = __shfl(vd01[2 * c + 1][dt], srcA); u.d[0] = hi ? b0 : a0;
                    a0 = __shfl(vd23[2 * c][dt], srcA); b0 = __shfl(vd23[2 * c + 1][dt], srcA); u.d[1] = hi ? b0 : a0;
                    a0 = __shfl(vd01[2 * c][dt], srcB); b0 = __shfl(vd01[2 * c + 1][dt], srcB); u.d[2] = hi ? b0 : a0;
                    a0 = __shfl(vd23[2 * c][dt], srcB); b0 = __shfl(vd23[2 * c + 1][dt], srcB); u.d[3] = hi ? b0 : a0;
                    vb[dt][c] = u.v;
                }
        }
    }
    __syncthreads();   // all xs reads done; attn-out may overwrite

    // ---- P2+P3: swapped QK^T -> in-register double softmax -> PV -> xs ----
    {
        const float* rpbh   = rpbf + h * 4096;
        const float* maskph = MP ? (maskp + (size_t)(b & (NWIN - 1)) * 4096) : nullptr;
        const float* mrow   = MP ? nullptr : (mask + (size_t)(b & (NWIN - 1)) * (NTOK * NTOK));

        #pragma unroll
        for (int nt = 0; nt < 4; ++nt) {
            f32x4 sv[4];
            #pragma unroll
            for (int mt = 0; mt < 4; ++mt) {
                f32x4 z = (f32x4){0.f, 0.f, 0.f, 0.f};
                sv[mt] = mfma16(kb[mt], qa[nt], z);   // sv[mt][j] = S[q=nt*16+r16][key=mt*16+g4+j]
            }
            const int qi = nt * 16 + r16;
            float s[4][4];
            if (MP) {
                #pragma unroll
                for (int mt = 0; mt < 4; ++mt) {
                    float4 r4 = *reinterpret_cast<const float4*>(rpbh + (qi << 6) + mt * 16 + g4);
                    float4 m4 = *reinterpret_cast<const float4*>(maskph + (qi << 6) + mt * 16 + g4);
                    s[mt][0] = sv[mt][0] + r4.x + m4.x;
                    s[mt][1] = sv[mt][1] + r4.y + m4.y;
                    s[mt][2] = sv[mt][2] + r4.z + m4.z;
                    s[mt][3] = sv[mt][3] + r4.w + m4.w;
                }
            } else {
                const int mbase = qi * NTOK;
                #pragma unroll
                for (int mt = 0; mt < 4; ++mt)
                    #pragma unroll
                    for (int j = 0; j < 4; ++j) {
                        const int key = mt * 16 + g4 + j;
                        float v = sv[mt][j] + rpbh[(qi << 6) + key];
                        if ((mt < 3 || (j == 0 && g == 0)) && qi < NTOK)
                            v += mrow[mbase + key];
                        s[mt][j] = v;
                    }
            }

            // softmax 1 (row qi spans lanes {r16, r16+16, r16+32, r16+48})
            float mx = -3.0e38f;
            #pragma unroll
            for (int mt = 0; mt < 4; ++mt)
                #pragma unroll
                for (int j = 0; j < 4; ++j) mx = fmaxf(mx, s[mt][j]);
            mx = fmaxf(mx, __shfl_xor(mx, 16));
            mx = fmaxf(mx, __shfl_xor(mx, 32));
            float e1[4][4];
            float sum1 = 0.f;
            #pragma unroll
            for (int mt = 0; mt < 4; ++mt)
                #pragma unroll
                for (int j = 0; j < 4; ++j) {
                    float t = __expf(s[mt][j] - mx);   // pad keys -> exact 0
                    e1[mt][j] = t; sum1 += t;
                }
            sum1 += __shfl_xor(sum1, 16);
            sum1 += __shfl_xor(sum1, 32);
            const float inv1 = __builtin_amdgcn_rcpf(sum1);

            // softmax 2 on p in [0,1]: pads give exp(0)=1 -> subtract 15
            float e2[4][4];
            float sum2 = 0.f;
            #pragma unroll
            for (int mt = 0; mt < 4; ++mt)
                #pragma unroll
                for (int j = 0; j < 4; ++j) {
                    float t = __expf(e1[mt][j] * inv1);
                    e2[mt][j] = t; sum2 += t;
                }
            sum2 += __shfl_xor(sum2, 16);
            sum2 += __shfl_xor(sum2, 32);
            sum2 -= 15.0f;
            const float inv2 = __builtin_amdgcn_rcpf(sum2);

            // pack P to bf16 dwords; zero pad keys
            u32 d01[4], d23[4];
            #pragma unroll
            for (int mt = 0; mt < 4; ++mt) {
                float p0 = e2[mt][0] * inv2, p1 = e2[mt][1] * inv2;
                float p2 = e2[mt][2] * inv2, p3 = e2[mt][3] * inv2;
                if (mt == 3) { p0 = (g == 0) ? p0 : 0.f; p1 = 0.f; p2 = 0.f; p3 = 0.f; }
                d01[mt] = pk2(p0, p1);
                d23[mt] = pk2(p2, p3);
            }
            // transpose to PV A-fragments
            u32 m0a0 = __shfl(d01[0], srcA), m0a1 = __shfl(d23[0], srcA);
            u32 m0b0 = __shfl(d01[0], srcB), m0b1 = __shfl(d23[0], srcB);
            u32 m1a0 = __shfl(d01[1], srcA), m1a1 = __shfl(d23[1], srcA);
            u32 m1b0 = __shfl(d01[1], srcB), m1b1 = __shfl(d23[1], srcB);
            u32 m2a0 = __shfl(d01[2], srcA), m2a1 = __shfl(d23[2], srcA);
            u32 m2b0 = __shfl(d01[2], srcB), m2b1 = __shfl(d23[2], srcB);
            u32 m3a0 = __shfl(d01[3], srcA), m3a1 = __shfl(d23[3], srcA);
            u32 m3b0 = __shfl(d01[3], srcB), m3b1 = __shfl(d23[3], srcB);

            union U8 { u32 d[4]; bf16x8 v; } ua, ub;
            ua.d[0] = lo ? m0a0 : m1a0;  ua.d[1] = lo ? m0a1 : m1a1;
            ua.d[2] = lo ? m0b0 : m1b0;  ua.d[3] = lo ? m0b1 : m1b1;
            ub.d[0] = lo ? m2a0 : m3a0;  ub.d[1] = lo ? m2a1 : m3a1;
            ub.d[2] = lo ? m2b0 : m3b0;  ub.d[3] = lo ? m2b1 : m3b1;

            // PV: out[q=nt*16+g4+j][d=dt*16+r16 (+h*32)] -> xs (attn-out)
            #pragma unroll
            for (int dt = 0; dt < 2; ++dt) {
                f32x4 z = (f32x4){0.f, 0.f, 0.f, 0.f};
                f32x4 o = mfma16(ua.v, vb[dt][0], z);
                o = mfma16(ub.v, vb[dt][1], o);
                const int dcol = h * 32 + dt * 16 + r16;
                #pragma unroll
                for (int j = 0; j < 4; ++j)
                    xs[nt * 16 + g4 + j][dcol] = (bf16_t)o[j];
            }
        }
    }
    __syncthreads();

    // ---- P4: final = attn_out @ proj_w + b.  Wave h owns cols [h*32, h*32+32) ----
    {
        #pragma unroll
        for (int n2 = 0; n2 < 2; ++n2) {
            const int col = h * 32 + n2 * 16 + r16;
            f32x4 acc[4];
            #pragma unroll
            for (int mt = 0; mt < 4; ++mt) acc[mt] = (f32x4){0.f, 0.f, 0.f, 0.f};
            #pragma unroll
            for (int ks = 0; ks < 3; ++ks) {
                bf16x8 bfr = *reinterpret_cast<const bf16x8*>(wpT + col * 96 + ks * 32 + g8);
                #pragma unroll
                for (int mt = 0; mt < 4; ++mt) {
                    bf16x8 oa = *reinterpret_cast<const bf16x8*>(&xs[mt * 16 + r16][ks * 32 + g8]);
                    acc[mt] = mfma16(oa, bfr, acc[mt]);
                }
            }
            const float pb = proj_b[col];
            #pragma unroll
            for (int mt = 0; mt < 4; ++mt)
                #pragma unroll
                for (int j = 0; j < 4; ++j) {
                    const int row = mt * 16 + g4 + j;
                    if (row < NTOK)
                        out[((size_t)b * NTOK + row) * CDIM + col] = acc[mt][j] + pb;
                }
        }
    }
}

extern "C" void kernel_launch(void* const* d_in, const int* in_sizes, int n_in,
                              void* d_out, int out_size, void* d_ws, size_t ws_size,
                              hipStream_t stream) {
    const float* x          = (const float*)d_in[0];
    const float* mask       = (const float*)d_in[1];
    const float* qkv_w      = (const float*)d_in[2];
    const float* qkv_b      = (const float*)d_in[3];
    const float* proj_w     = (const float*)d_in[4];
    const float* proj_b     = (const float*)d_in[5];
    const float* bias_table = (const float*)d_in[6];
    const int*   rel_idx    = (const int*)d_in[7];
    float* out = (float*)d_out;

    char* ws = (char*)d_ws;
    bf16_t* wqT  = (bf16_t*)(ws);                      // 55296 B
    bf16_t* wpT  = (bf16_t*)(ws + 55296);              // 18432 B
    float*  rpbf = (float*) (ws + 55296 + 18432);      // 49152 B
    const size_t maskp_off = 122880;
    const size_t maskp_sz  = (size_t)NWIN * 64 * 64 * 4;   // 16.78 MB
    const bool mp = ws_size >= maskp_off + maskp_sz;
    float* maskp = mp ? (float*)(ws + maskp_off) : nullptr;

    prep_kernel<<<mp ? 2048 : 64, 256, 0, stream>>>(qkv_w, proj_w, bias_table, rel_idx,
                                                    mask, wqT, wpT, rpbf, maskp);

    const int nwin = in_sizes[0] / (NTOK * CDIM);      // 16384
    if (mp)
        wattn_kernel<true><<<nwin, 192, 0, stream>>>(x, mask, maskp, qkv_b, proj_b,
                                                     wqT, wpT, rpbf, out);
    else
        wattn_kernel<false><<<nwin, 192, 0, stream>>>(x, mask, maskp, qkv_b, proj_b,
                                                      wqT, wpT, rpbf, out);
}